// Round 1
// baseline (608.572 us; speedup 1.0000x reference)
//
#include <hip/hip_runtime.h>
#include <hip/hip_bf16.h>

#define N 8192
#define FIN 256
#define FOUT 64
#define NEG_SLOPE 0.01f
#define ROWS 32
#define CHUNK 256
#define NCHUNK (N / CHUNK)

typedef float f32x4 __attribute__((ext_vector_type(4)));
typedef __bf16 bf16x8 __attribute__((ext_vector_type(8)));

__device__ __forceinline__ float lk(float x) { return x >= 0.f ? x : NEG_SLOPE * x; }

// ---------------------------------------------------------------------------
// K1: Wh = h@W (fp32), stored as bf16 in MFMA B-fragment layout:
//     WhB[(kg*64 + n)*8 + e] = bf16(Wh[kg*8+e][n])   (kg = k/8)
// plus f1 = Wh@a1, f2 = Wh@a2 (fp32).
// 256 threads, 16 rows/block. W (64KB) + h rows (16KB) staged in LDS.
// ---------------------------------------------------------------------------
__global__ __launch_bounds__(256) void gat_k1(const float* __restrict__ h,
                                              const float* __restrict__ W,
                                              const float* __restrict__ a,
                                              unsigned short* __restrict__ WhB,
                                              float* __restrict__ f1,
                                              float* __restrict__ f2) {
  __shared__ float Ws[FIN * FOUT];   // 64KB
  __shared__ float hs[16 * FIN];     // 16KB
  const int t = threadIdx.x;
  const int lane = t & 63;
  const int w = t >> 6;              // 0..3
  const size_t row0 = (size_t)blockIdx.x * 16;

  for (int i = t; i < FIN * FOUT / 4; i += 256)
    ((f32x4*)Ws)[i] = ((const f32x4*)W)[i];
  for (int i = t; i < 16 * FIN / 4; i += 256)
    ((f32x4*)hs)[i] = ((const f32x4*)(h + row0 * FIN))[i];
  __syncthreads();

  float acc[4] = {0.f, 0.f, 0.f, 0.f};
  #pragma unroll 8
  for (int c = 0; c < FIN; ++c) {
    const float wv = Ws[c * FOUT + lane];
    #pragma unroll
    for (int i = 0; i < 4; ++i)
      acc[i] = fmaf(hs[(w + 4 * i) * FIN + c], wv, acc[i]);
  }

  const float a1k = a[lane];
  const float a2k = a[FOUT + lane];
  #pragma unroll
  for (int i = 0; i < 4; ++i) {
    const size_t row = row0 + (w + 4 * i);
    WhB[(((row >> 3) * 64) + lane) * 8 + (row & 7)] =
        __builtin_bit_cast(unsigned short, __float2bfloat16(acc[i]));
    float p1 = acc[i] * a1k, p2 = acc[i] * a2k;
    #pragma unroll
    for (int off = 32; off; off >>= 1) {
      p1 += __shfl_down(p1, off);
      p2 += __shfl_down(p2, off);
    }
    if (lane == 0) { f1[row] = p1; f2[row] = p2; }
  }
}

// ---------------------------------------------------------------------------
// K2: fused mask + softmax + attention-write + PV (attention @ Wh via MFMA).
// 512 threads (8 waves), 32 rows/block, 256 blocks.
// Phase 1 : single adj sweep -> mask bits in LDS + masked max of f2 per row.
// Phase1.5: Z per row from LDS mask + f2 (no global traffic).
// Phase 2 : per 256-j chunk: compute att (f32 -> global, bf16 -> swizzled LDS
//           tile), then 8x mfma_f32_16x16x32_bf16 per wave; each wave owns one
//           16x16 output tile (mt = w>>2, nt = w&3).
// ---------------------------------------------------------------------------
__global__ __launch_bounds__(512) void gat_k2(const float* __restrict__ adj,
                                              const float* __restrict__ f1g,
                                              const float* __restrict__ f2g,
                                              const unsigned short* __restrict__ WhB,
                                              float* __restrict__ att,
                                              float* __restrict__ hp) {
  __shared__ float f2s[N];                              // 32KB
  __shared__ unsigned long long msk[ROWS][NCHUNK][4];   // 32KB, bit l of [r][c][b] = adj[r][c*256+l*4+b]>0
  __shared__ float f1s[ROWS], ms[ROWS], iz[ROWS];
  __shared__ __align__(16) unsigned char attb[ROWS * CHUNK * 2];  // 16KB bf16 tile, XOR-swizzled

  const int t = threadIdx.x;
  const int lane = t & 63;
  const int w = t >> 6;  // 0..7
  const size_t row0 = (size_t)blockIdx.x * ROWS;

  for (int i = t; i < N / 4; i += 512)
    ((f32x4*)f2s)[i] = ((const f32x4*)f2g)[i];
  if (t < ROWS) f1s[t] = f1g[row0 + t];
  __syncthreads();

  // ---- phase 1: mask + masked max(f2) per row (wave w owns rows 4w..4w+3)
  for (int rr = 0; rr < 4; ++rr) {
    const int r = w * 4 + rr;
    const f32x4* arow = (const f32x4*)(adj + (row0 + r) * (size_t)N);
    float mx = -INFINITY;
    #pragma unroll 4
    for (int c = 0; c < NCHUNK; ++c) {
      const f32x4 v = arow[c * 64 + lane];
      const unsigned long long b0 = __ballot(v.x > 0.f);
      const unsigned long long b1 = __ballot(v.y > 0.f);
      const unsigned long long b2 = __ballot(v.z > 0.f);
      const unsigned long long b3 = __ballot(v.w > 0.f);
      if (lane == 0) {
        msk[r][c][0] = b0; msk[r][c][1] = b1;
        msk[r][c][2] = b2; msk[r][c][3] = b3;
      }
      const f32x4 f = *(const f32x4*)&f2s[c * CHUNK + lane * 4];
      if (v.x > 0.f) mx = fmaxf(mx, f.x);
      if (v.y > 0.f) mx = fmaxf(mx, f.y);
      if (v.z > 0.f) mx = fmaxf(mx, f.z);
      if (v.w > 0.f) mx = fmaxf(mx, f.w);
    }
    #pragma unroll
    for (int off = 32; off; off >>= 1) mx = fmaxf(mx, __shfl_xor(mx, off));
    if (lane == 0) ms[r] = lk(f1s[r] + mx);  // leaky monotonic => row max
  }

  // ---- phase 1.5: Z per row (LDS only)
  for (int rr = 0; rr < 4; ++rr) {
    const int r = w * 4 + rr;
    const float f1r = f1s[r];
    const float m = ms[r];
    float s = 0.f;
    for (int c = 0; c < NCHUNK; ++c) {
      const unsigned long long b0 = msk[r][c][0], b1 = msk[r][c][1];
      const unsigned long long b2 = msk[r][c][2], b3 = msk[r][c][3];
      const f32x4 f = *(const f32x4*)&f2s[c * CHUNK + lane * 4];
      if ((b0 >> lane) & 1ull) s += __expf(lk(f1r + f.x) - m);
      if ((b1 >> lane) & 1ull) s += __expf(lk(f1r + f.y) - m);
      if ((b2 >> lane) & 1ull) s += __expf(lk(f1r + f.z) - m);
      if ((b3 >> lane) & 1ull) s += __expf(lk(f1r + f.w) - m);
    }
    #pragma unroll
    for (int off = 32; off; off >>= 1) s += __shfl_xor(s, off);
    if (lane == 0) iz[r] = 1.f / s;
  }
  __syncthreads();

  // ---- phase 2: attention write + PV MFMA
  const int mt = w >> 2, nt = w & 3;
  f32x4 acc = {0.f, 0.f, 0.f, 0.f};
  for (int c = 0; c < NCHUNK; ++c) {
    for (int rr = 0; rr < 4; ++rr) {
      const int r = w * 4 + rr;
      const float f1r = f1s[r], m = ms[r], z = iz[r];
      const unsigned long long b0 = msk[r][c][0], b1 = msk[r][c][1];
      const unsigned long long b2 = msk[r][c][2], b3 = msk[r][c][3];
      const f32x4 f = *(const f32x4*)&f2s[c * CHUNK + lane * 4];
      f32x4 p;
      p.x = ((b0 >> lane) & 1ull) ? __expf(lk(f1r + f.x) - m) * z : 0.f;
      p.y = ((b1 >> lane) & 1ull) ? __expf(lk(f1r + f.y) - m) * z : 0.f;
      p.z = ((b2 >> lane) & 1ull) ? __expf(lk(f1r + f.z) - m) * z : 0.f;
      p.w = ((b3 >> lane) & 1ull) ? __expf(lk(f1r + f.w) - m) * z : 0.f;
      *(f32x4*)(att + (row0 + r) * (size_t)N + c * CHUNK + lane * 4) = p;
      // bf16 pack -> swizzled LDS
      const unsigned long long pk =
          (unsigned long long)__builtin_bit_cast(unsigned short, __float2bfloat16(p.x)) |
          ((unsigned long long)__builtin_bit_cast(unsigned short, __float2bfloat16(p.y)) << 16) |
          ((unsigned long long)__builtin_bit_cast(unsigned short, __float2bfloat16(p.z)) << 32) |
          ((unsigned long long)__builtin_bit_cast(unsigned short, __float2bfloat16(p.w)) << 48);
      int byte = r * (CHUNK * 2) + lane * 8;
      byte ^= (r & 7) << 4;
      *(unsigned long long*)(attb + byte) = pk;
    }
    __syncthreads();
    #pragma unroll
    for (int s = 0; s < 8; ++s) {
      // A: att[M=16][K=32], lane: row = mt*16 + (l&15), k = s*32 + (l>>4)*8 + e
      const int arow_ = mt * 16 + (lane & 15);
      int ab = arow_ * (CHUNK * 2) + s * 64 + (lane >> 4) * 16;
      ab ^= (arow_ & 7) << 4;
      const bf16x8 afrag = *(const bf16x8*)(attb + ab);
      // B: Wh[K][N=16], lane: n = nt*16 + (l&15), k-group kg = c*32 + s*4 + (l>>4)
      const int kg = c * 32 + s * 4 + (lane >> 4);
      const bf16x8 bfrag = *(const bf16x8*)(WhB + ((size_t)kg * 64 + nt * 16 + (lane & 15)) * 8);
      acc = __builtin_amdgcn_mfma_f32_16x16x32_bf16(afrag, bfrag, acc, 0, 0, 0);
    }
    __syncthreads();
  }

  // ---- epilogue: h_prime. C/D layout: col = lane&15, row = (lane>>4)*4 + reg
  {
    const int col = nt * 16 + (lane & 15);
    const int rbase = mt * 16 + (lane >> 4) * 4;
    #pragma unroll
    for (int q = 0; q < 4; ++q)
      hp[(row0 + rbase + q) * FOUT + col] = acc[q];
  }
}

extern "C" void kernel_launch(void* const* d_in, const int* in_sizes, int n_in,
                              void* d_out, int out_size, void* d_ws, size_t ws_size,
                              hipStream_t stream) {
  const float* h   = (const float*)d_in[0];
  const float* adj = (const float*)d_in[1];
  const float* W   = (const float*)d_in[2];
  const float* a   = (const float*)d_in[3];
  // d_in[4] = rel (unused)

  float* hp  = (float*)d_out;                 // 8192*64
  float* att = hp + (size_t)N * FOUT;         // 8192*8192

  unsigned short* WhB = (unsigned short*)d_ws;                  // 1 MB (bf16 frag layout)
  float* f1 = (float*)((char*)d_ws + (size_t)N * FOUT * 2);     // 32 KB
  float* f2 = f1 + N;                                           // 32 KB

  gat_k1<<<N / 16, 256, 0, stream>>>(h, W, a, WhB, f1, f2);
  gat_k2<<<N / ROWS, 512, 0, stream>>>(adj, f1, f2, WhB, att, hp);
}

// Round 2
// 534.463 us; speedup vs baseline: 1.1387x; 1.1387x over previous
//
#include <hip/hip_runtime.h>
#include <hip/hip_bf16.h>

#define N 8192
#define FIN 256
#define FOUT 64
#define NEG_SLOPE 0.01f
#define CHUNK 256
#define NCHUNK (N / CHUNK)
#define ROWS_B 8   // rows per block in k2b

typedef float f32x4 __attribute__((ext_vector_type(4)));
typedef __bf16 bf16x8 __attribute__((ext_vector_type(8)));
typedef unsigned long long ull;

__device__ __forceinline__ float lk(float x) { return x >= 0.f ? x : NEG_SLOPE * x; }

// ---------------------------------------------------------------------------
// K1: Wh = h@W (fp32). Outputs:
//   WhB bf16 in MFMA B-frag layout: WhB[(kg*64+n)*8+e] = bf16(Wh[kg*8+e][n])
//   f1 = Wh@a1, f2 = Wh@a2 (fp32)
// 256 thr, 16 rows/block. W in LDS (64KB); h read as uniform global f32x4.
// ---------------------------------------------------------------------------
__global__ __launch_bounds__(256) void gat_k1(const float* __restrict__ h,
                                              const float* __restrict__ W,
                                              const float* __restrict__ a,
                                              unsigned short* __restrict__ WhB,
                                              float* __restrict__ f1,
                                              float* __restrict__ f2) {
  __shared__ float Ws[FIN * FOUT];   // 64KB
  const int t = threadIdx.x;
  const int lane = t & 63;
  const int w = t >> 6;              // 0..3
  const size_t row0 = (size_t)blockIdx.x * 16;

  for (int i = t; i < FIN * FOUT / 4; i += 256)
    ((f32x4*)Ws)[i] = ((const f32x4*)W)[i];
  __syncthreads();

  const float* h0 = h + row0 * FIN;
  float acc[4] = {0.f, 0.f, 0.f, 0.f};   // rows w+4i, col = lane
  #pragma unroll 4
  for (int c4 = 0; c4 < FIN; c4 += 4) {
    const f32x4 hv0 = *(const f32x4*)(h0 + (w + 0)  * FIN + c4);
    const f32x4 hv1 = *(const f32x4*)(h0 + (w + 4)  * FIN + c4);
    const f32x4 hv2 = *(const f32x4*)(h0 + (w + 8)  * FIN + c4);
    const f32x4 hv3 = *(const f32x4*)(h0 + (w + 12) * FIN + c4);
    #pragma unroll
    for (int j = 0; j < 4; ++j) {
      const float wv = Ws[(c4 + j) * FOUT + lane];
      acc[0] = fmaf(hv0[j], wv, acc[0]);
      acc[1] = fmaf(hv1[j], wv, acc[1]);
      acc[2] = fmaf(hv2[j], wv, acc[2]);
      acc[3] = fmaf(hv3[j], wv, acc[3]);
    }
  }

  const float a1k = a[lane];
  const float a2k = a[FOUT + lane];
  #pragma unroll
  for (int i = 0; i < 4; ++i) {
    const size_t row = row0 + (w + 4 * i);
    WhB[(((row >> 3) * 64) + lane) * 8 + (row & 7)] =
        __builtin_bit_cast(unsigned short, __float2bfloat16(acc[i]));
    float p1 = acc[i] * a1k, p2 = acc[i] * a2k;
    #pragma unroll
    for (int off = 32; off; off >>= 1) {
      p1 += __shfl_down(p1, off);
      p2 += __shfl_down(p2, off);
    }
    if (lane == 0) { f1[row] = p1; f2[row] = p2; }
  }
}

// ---------------------------------------------------------------------------
// K2a: one adj sweep -> mask bits (global, 8MB) + row sum of exp (m=0).
// 1024 blocks x 512 thr; one wave per row. f2 staged in LDS (32KB).
// ---------------------------------------------------------------------------
__global__ __launch_bounds__(512) void gat_k2a(const float* __restrict__ adj,
                                               const float* __restrict__ f1g,
                                               const float* __restrict__ f2g,
                                               ull* __restrict__ mskg,
                                               float* __restrict__ izg) {
  __shared__ float f2s[N];   // 32KB
  const int t = threadIdx.x;
  const int lane = t & 63;
  const int w = t >> 6;      // 0..7
  for (int i = t; i < N / 4; i += 512)
    ((f32x4*)f2s)[i] = ((const f32x4*)f2g)[i];
  __syncthreads();

  const int row = blockIdx.x * 8 + w;
  const float f1r = f1g[row];
  const f32x4* arow = (const f32x4*)(adj + (size_t)row * N);
  ull* mrow = mskg + (size_t)row * (NCHUNK * 4);

  float s = 0.f;
  #pragma unroll 8
  for (int c = 0; c < NCHUNK; ++c) {
    const f32x4 v = arow[c * 64 + lane];
    const f32x4 f = *(const f32x4*)&f2s[c * CHUNK + lane * 4];
    const ull b0 = __ballot(v.x > 0.f);
    const ull b1 = __ballot(v.y > 0.f);
    const ull b2 = __ballot(v.z > 0.f);
    const ull b3 = __ballot(v.w > 0.f);
    const ull bb = lane == 0 ? b0 : lane == 1 ? b1 : lane == 2 ? b2 : b3;
    if (lane < 4) mrow[c * 4 + lane] = bb;
    s += (v.x > 0.f) ? __expf(lk(f1r + f.x)) : 0.f;
    s += (v.y > 0.f) ? __expf(lk(f1r + f.y)) : 0.f;
    s += (v.z > 0.f) ? __expf(lk(f1r + f.z)) : 0.f;
    s += (v.w > 0.f) ? __expf(lk(f1r + f.w)) : 0.f;
  }
  #pragma unroll
  for (int off = 32; off; off >>= 1) s += __shfl_xor(s, off);
  if (lane == 0) izg[row] = 1.f / s;
}

// ---------------------------------------------------------------------------
// K2b: att = exp(lk(f1+f2))*iz (masked), nontemporal write + PV via MFMA.
// 1024 blocks x 512 thr, 8 rows/block; wave w owns row w for the att phase.
// MFMA: 16x16x32 with rows 8..15 of A zeroed; wave (ks=w>>2, nt=w&3) does a
// K-split half; cross-ks reduce in LDS at the end.
// ---------------------------------------------------------------------------
__global__ __launch_bounds__(512) void gat_k2b(const ull* __restrict__ mskg,
                                               const float* __restrict__ f1g,
                                               const float* __restrict__ f2g,
                                               const float* __restrict__ izg,
                                               const unsigned short* __restrict__ WhB,
                                               float* __restrict__ att,
                                               float* __restrict__ hp) {
  __shared__ ull msk[ROWS_B * NCHUNK * 4];                        // 8KB
  __shared__ __align__(16) unsigned char attb[16 * CHUNK * 2];    // 16x512B = 8KB (rows 8..15 stay 0)
  __shared__ float red[4][64][4];                                 // 4KB
  __shared__ float f1s[ROWS_B], izs[ROWS_B];

  const int t = threadIdx.x;
  const int lane = t & 63;
  const int w = t >> 6;  // 0..7
  const size_t row0 = (size_t)blockIdx.x * ROWS_B;

  for (int i = t; i < ROWS_B * NCHUNK * 4; i += 512)
    msk[i] = mskg[row0 * (NCHUNK * 4) + i];
  for (int i = t; i < 16 * CHUNK * 2 / 4; i += 512)
    ((unsigned int*)attb)[i] = 0u;
  if (t < ROWS_B) { f1s[t] = f1g[row0 + t]; izs[t] = izg[row0 + t]; }
  __syncthreads();

  const int ks = w >> 2, nt = w & 3;
  const int r = w;  // att-phase row
  const float f1r = f1s[r], z = izs[r];
  f32x4 acc = {0.f, 0.f, 0.f, 0.f};

  for (int c = 0; c < NCHUNK; ++c) {
    // ---- att phase: wave w computes row w, 256 cols
    const f32x4 f = *(const f32x4*)&f2g[c * CHUNK + lane * 4];
    const ull b0 = msk[r * (NCHUNK * 4) + c * 4 + 0];
    const ull b1 = msk[r * (NCHUNK * 4) + c * 4 + 1];
    const ull b2 = msk[r * (NCHUNK * 4) + c * 4 + 2];
    const ull b3 = msk[r * (NCHUNK * 4) + c * 4 + 3];
    f32x4 p;
    p.x = ((b0 >> lane) & 1ull) ? __expf(lk(f1r + f.x)) * z : 0.f;
    p.y = ((b1 >> lane) & 1ull) ? __expf(lk(f1r + f.y)) * z : 0.f;
    p.z = ((b2 >> lane) & 1ull) ? __expf(lk(f1r + f.z)) * z : 0.f;
    p.w = ((b3 >> lane) & 1ull) ? __expf(lk(f1r + f.w)) * z : 0.f;
    __builtin_nontemporal_store(p, (f32x4*)(att + (row0 + r) * (size_t)N + c * CHUNK + lane * 4));
    const ull pk =
        (ull)__builtin_bit_cast(unsigned short, __float2bfloat16(p.x)) |
        ((ull)__builtin_bit_cast(unsigned short, __float2bfloat16(p.y)) << 16) |
        ((ull)__builtin_bit_cast(unsigned short, __float2bfloat16(p.z)) << 32) |
        ((ull)__builtin_bit_cast(unsigned short, __float2bfloat16(p.w)) << 48);
    int byte = r * (CHUNK * 2) + lane * 8;
    byte ^= (r & 7) << 4;
    *(ull*)(attb + byte) = pk;
    __syncthreads();

    // ---- PV phase: 4 MFMA per wave (K-split)
    #pragma unroll
    for (int s = 0; s < 4; ++s) {
      const int mf = ks * 4 + s;                 // 0..7, K-slot of 32 within chunk
      const int arow_ = lane & 15;
      int ab = arow_ * (CHUNK * 2) + mf * 64 + (lane >> 4) * 16;
      ab ^= (arow_ & 7) << 4;
      const bf16x8 afrag = *(const bf16x8*)(attb + ab);
      const int kg = c * 32 + mf * 4 + (lane >> 4);
      const bf16x8 bfrag = *(const bf16x8*)(WhB + ((size_t)kg * 64 + nt * 16 + (lane & 15)) * 8);
      acc = __builtin_amdgcn_mfma_f32_16x16x32_bf16(afrag, bfrag, acc, 0, 0, 0);
    }
    __syncthreads();
  }

  // ---- reduce K-split halves, write hp (rows 0..7 only)
  if (ks == 1) *(f32x4*)&red[nt][lane][0] = acc;
  __syncthreads();
  if (ks == 0) {
    const f32x4 o = acc + *(const f32x4*)&red[nt][lane][0];
    const int col = nt * 16 + (lane & 15);
    const int rbase = (lane >> 4) * 4;           // 0,4,8,12
    if (rbase < ROWS_B) {
      #pragma unroll
      for (int q = 0; q < 4; ++q)
        hp[(row0 + rbase + q) * FOUT + col] = o[q];
    }
  }
}

extern "C" void kernel_launch(void* const* d_in, const int* in_sizes, int n_in,
                              void* d_out, int out_size, void* d_ws, size_t ws_size,
                              hipStream_t stream) {
  const float* h   = (const float*)d_in[0];
  const float* adj = (const float*)d_in[1];
  const float* W   = (const float*)d_in[2];
  const float* a   = (const float*)d_in[3];

  float* hp  = (float*)d_out;                 // 8192*64
  float* att = hp + (size_t)N * FOUT;         // 8192*8192

  // workspace layout (total ~9.2MB)
  unsigned short* WhB = (unsigned short*)d_ws;                        // 1MB
  float* f1 = (float*)((char*)d_ws + (size_t)N * FOUT * 2);           // 32KB
  float* f2 = f1 + N;                                                 // 32KB
  float* iz = f2 + N;                                                 // 32KB
  ull*   msk = (ull*)(iz + N);                                        // 8MB

  gat_k1 <<<N / 16, 256, 0, stream>>>(h, W, a, WhB, f1, f2);
  gat_k2a<<<N / 8, 512, 0, stream>>>(adj, f1, f2, msk, iz);
  gat_k2b<<<N / ROWS_B, 512, 0, stream>>>(msk, f1, f2, iz, WhB, att, hp);
}

// Round 4
// 521.200 us; speedup vs baseline: 1.1676x; 1.0254x over previous
//
#include <hip/hip_runtime.h>
#include <hip/hip_bf16.h>

#define N 8192
#define FIN 256
#define FOUT 64
#define NEG_SLOPE 0.01f
#define CHUNK 256
#define NCHUNK (N / CHUNK)
#define RB 32                 // rows per block in k2b
#define MWORDS (NCHUNK * 4)   // 64-bit mask words per row (=128)

typedef float f32x4 __attribute__((ext_vector_type(4)));
typedef __bf16 bf16x8 __attribute__((ext_vector_type(8)));
typedef unsigned long long ull;

__device__ __forceinline__ float lk(float x) { return x >= 0.f ? x : NEG_SLOPE * x; }

// ---------------------------------------------------------------------------
// K1: Wh = h@W (fp32). Outputs:
//   WhB bf16 in MFMA B-frag layout: WhB[(kg*64+n)*8+e] = bf16(Wh[kg*8+e][n])
//   f1 = Wh@a1, f2 = Wh@a2 (fp32)
// 256 thr, 16 rows/block. W in LDS (64KB); h read as wave-uniform f32x4.
// ---------------------------------------------------------------------------
__global__ __launch_bounds__(256) void gat_k1(const float* __restrict__ h,
                                              const float* __restrict__ W,
                                              const float* __restrict__ a,
                                              unsigned short* __restrict__ WhB,
                                              float* __restrict__ f1,
                                              float* __restrict__ f2) {
  __shared__ float Ws[FIN * FOUT];   // 64KB
  const int t = threadIdx.x;
  const int lane = t & 63;
  const int w = t >> 6;              // 0..3
  const size_t row0 = (size_t)blockIdx.x * 16;

  for (int i = t; i < FIN * FOUT / 4; i += 256)
    ((f32x4*)Ws)[i] = ((const f32x4*)W)[i];
  __syncthreads();

  const float* h0 = h + row0 * FIN;
  float acc[4] = {0.f, 0.f, 0.f, 0.f};   // rows w+4i, col = lane
  #pragma unroll 4
  for (int c4 = 0; c4 < FIN; c4 += 4) {
    const f32x4 hv0 = *(const f32x4*)(h0 + (w + 0)  * FIN + c4);
    const f32x4 hv1 = *(const f32x4*)(h0 + (w + 4)  * FIN + c4);
    const f32x4 hv2 = *(const f32x4*)(h0 + (w + 8)  * FIN + c4);
    const f32x4 hv3 = *(const f32x4*)(h0 + (w + 12) * FIN + c4);
    #pragma unroll
    for (int j = 0; j < 4; ++j) {
      const float wv = Ws[(c4 + j) * FOUT + lane];
      acc[0] = fmaf(hv0[j], wv, acc[0]);
      acc[1] = fmaf(hv1[j], wv, acc[1]);
      acc[2] = fmaf(hv2[j], wv, acc[2]);
      acc[3] = fmaf(hv3[j], wv, acc[3]);
    }
  }

  const float a1k = a[lane];
  const float a2k = a[FOUT + lane];
  #pragma unroll
  for (int i = 0; i < 4; ++i) {
    const size_t row = row0 + (w + 4 * i);
    WhB[(((row >> 3) * 64) + lane) * 8 + (row & 7)] =
        __builtin_bit_cast(unsigned short, __float2bfloat16(acc[i]));
    float p1 = acc[i] * a1k, p2 = acc[i] * a2k;
    #pragma unroll
    for (int off = 32; off; off >>= 1) {
      p1 += __shfl_down(p1, off);
      p2 += __shfl_down(p2, off);
    }
    if (lane == 0) { f1[row] = p1; f2[row] = p2; }
  }
}

// ---------------------------------------------------------------------------
// K2a: one adj sweep (NT loads) -> mask bits (global, 8MB) + row expsum (m=0).
// 1024 blocks x 512 thr; one wave per row. No LDS; f2 served from L1/L2.
// ---------------------------------------------------------------------------
__global__ __launch_bounds__(512) void gat_k2a(const float* __restrict__ adj,
                                               const float* __restrict__ f1g,
                                               const float* __restrict__ f2g,
                                               ull* __restrict__ mskg,
                                               float* __restrict__ izg) {
  const int t = threadIdx.x;
  const int lane = t & 63;
  const int w = t >> 6;      // 0..7
  const int row = blockIdx.x * 8 + w;
  const float f1r = f1g[row];
  const f32x4* arow = (const f32x4*)(adj + (size_t)row * N);
  ull* mrow = mskg + (size_t)row * MWORDS;

  float s = 0.f;
  #pragma unroll 4
  for (int c = 0; c < NCHUNK; ++c) {
    const f32x4 v = __builtin_nontemporal_load(arow + c * 64 + lane);
    const f32x4 f = *(const f32x4*)&f2g[c * CHUNK + lane * 4];
    const ull b0 = __ballot(v.x > 0.f);
    const ull b1 = __ballot(v.y > 0.f);
    const ull b2 = __ballot(v.z > 0.f);
    const ull b3 = __ballot(v.w > 0.f);
    const ull bb = lane == 0 ? b0 : lane == 1 ? b1 : lane == 2 ? b2 : b3;
    if (lane < 4) mrow[c * 4 + lane] = bb;
    s += (v.x > 0.f) ? __expf(lk(f1r + f.x)) : 0.f;
    s += (v.y > 0.f) ? __expf(lk(f1r + f.y)) : 0.f;
    s += (v.z > 0.f) ? __expf(lk(f1r + f.z)) : 0.f;
    s += (v.w > 0.f) ? __expf(lk(f1r + f.w)) : 0.f;
  }
  #pragma unroll
  for (int off = 32; off; off >>= 1) s += __shfl_xor(s, off);
  if (lane == 0) izg[row] = 1.f / s;
}

// ---------------------------------------------------------------------------
// K2b: att = exp(lk(f1+f2))*iz (masked) -> NT store; PV via MFMA (bf16).
// 256 blocks x 512 thr, 32 rows/block. Wave w computes att rows 4w..4w+3;
// MFMA: wave (mt=w>>2, nt=w&3) owns C tile rows mt*16.., cols nt*16.., full
// K per chunk (8 x mfma_16x16x32). att LDS tile double-buffered, XOR-swizzled
// -> ONE barrier per chunk. Masks are wave-uniform global loads (L1-hot).
// ---------------------------------------------------------------------------
__global__ __launch_bounds__(512) void gat_k2b(const ull* __restrict__ mskg,
                                               const float* __restrict__ f1g,
                                               const float* __restrict__ f2g,
                                               const float* __restrict__ izg,
                                               const unsigned short* __restrict__ WhB,
                                               float* __restrict__ att,
                                               float* __restrict__ hp) {
  __shared__ __align__(16) unsigned char attb[2][RB * CHUNK * 2];  // 2 x 16KB
  const int t = threadIdx.x;
  const int lane = t & 63;
  const int w = t >> 6;          // 0..7
  const int mt = w >> 2, nt = w & 3;
  const size_t row0 = (size_t)blockIdx.x * RB;

  float f1r_[4], z_[4];
  #pragma unroll
  for (int rr = 0; rr < 4; ++rr) {
    f1r_[rr] = f1g[row0 + 4 * w + rr];
    z_[rr]   = izg[row0 + 4 * w + rr];
  }

  f32x4 acc = {0.f, 0.f, 0.f, 0.f};

  #pragma unroll 2
  for (int c = 0; c < NCHUNK; ++c) {
    unsigned char* ab = attb[c & 1];
    // ---- stage phase: 4 att rows per wave
    const f32x4 f = *(const f32x4*)&f2g[c * CHUNK + lane * 4];
    #pragma unroll
    for (int rr = 0; rr < 4; ++rr) {
      const int r = 4 * w + rr;
      const ull* mrow = mskg + (row0 + r) * (size_t)MWORDS + c * 4;
      const ull b0 = mrow[0], b1 = mrow[1], b2 = mrow[2], b3 = mrow[3];
      f32x4 p;
      p.x = ((b0 >> lane) & 1ull) ? __expf(lk(f1r_[rr] + f.x)) * z_[rr] : 0.f;
      p.y = ((b1 >> lane) & 1ull) ? __expf(lk(f1r_[rr] + f.y)) * z_[rr] : 0.f;
      p.z = ((b2 >> lane) & 1ull) ? __expf(lk(f1r_[rr] + f.z)) * z_[rr] : 0.f;
      p.w = ((b3 >> lane) & 1ull) ? __expf(lk(f1r_[rr] + f.w)) * z_[rr] : 0.f;
      __builtin_nontemporal_store(p, (f32x4*)(att + (row0 + r) * (size_t)N + c * CHUNK + lane * 4));
      const ull pk =
          (ull)__builtin_bit_cast(unsigned short, __float2bfloat16(p.x)) |
          ((ull)__builtin_bit_cast(unsigned short, __float2bfloat16(p.y)) << 16) |
          ((ull)__builtin_bit_cast(unsigned short, __float2bfloat16(p.z)) << 32) |
          ((ull)__builtin_bit_cast(unsigned short, __float2bfloat16(p.w)) << 48);
      int byte = r * (CHUNK * 2) + lane * 8;
      byte ^= (r & 7) << 4;
      *(ull*)(ab + byte) = pk;
    }
    __syncthreads();
    // ---- PV phase: 8 MFMA per wave (full K of the chunk)
    #pragma unroll
    for (int s = 0; s < 8; ++s) {
      const int arow_ = mt * 16 + (lane & 15);
      int off = arow_ * (CHUNK * 2) + s * 64 + (lane >> 4) * 16;
      off ^= (arow_ & 7) << 4;
      const bf16x8 afrag = *(const bf16x8*)(ab + off);
      const int kg = c * 32 + s * 4 + (lane >> 4);
      const bf16x8 bfrag = *(const bf16x8*)(WhB + ((size_t)kg * 64 + nt * 16 + (lane & 15)) * 8);
      acc = __builtin_amdgcn_mfma_f32_16x16x32_bf16(afrag, bfrag, acc, 0, 0, 0);
    }
    // no second barrier: next iteration writes the other buffer; the c+2
    // overwrite of this buffer is fenced by the barrier at c+1.
  }

  // ---- epilogue: C/D layout col = lane&15, row = (lane>>4)*4 + q
  const int col = nt * 16 + (lane & 15);
  const int rbase = mt * 16 + (lane >> 4) * 4;
  #pragma unroll
  for (int q = 0; q < 4; ++q)
    hp[(row0 + rbase + q) * FOUT + col] = acc[q];
}

extern "C" void kernel_launch(void* const* d_in, const int* in_sizes, int n_in,
                              void* d_out, int out_size, void* d_ws, size_t ws_size,
                              hipStream_t stream) {
  const float* h   = (const float*)d_in[0];
  const float* adj = (const float*)d_in[1];
  const float* W   = (const float*)d_in[2];
  const float* a   = (const float*)d_in[3];

  float* hp  = (float*)d_out;                 // 8192*64
  float* att = hp + (size_t)N * FOUT;         // 8192*8192

  // workspace layout (total ~9.2MB)
  unsigned short* WhB = (unsigned short*)d_ws;                        // 1MB
  float* f1 = (float*)((char*)d_ws + (size_t)N * FOUT * 2);           // 32KB
  float* f2 = f1 + N;                                                 // 32KB
  float* iz = f2 + N;                                                 // 32KB
  ull*   msk = (ull*)(iz + N);                                        // 8MB

  gat_k1 <<<N / 16, 256, 0, stream>>>(h, W, a, WhB, f1, f2);
  gat_k2a<<<N / 8, 512, 0, stream>>>(adj, f1, f2, msk, iz);
  gat_k2b<<<N / RB, 512, 0, stream>>>(msk, f1, f2, iz, WhB, att, hp);
}

// Round 5
// 511.140 us; speedup vs baseline: 1.1906x; 1.0197x over previous
//
#include <hip/hip_runtime.h>
#include <hip/hip_bf16.h>

#define N 8192
#define FIN 256
#define FOUT 64
#define NEG_SLOPE 0.01f
#define CHUNK 256
#define NCHUNK (N / CHUNK)   // 32
#define RB 8                 // rows per block in k2
#define MW (NCHUNK * 4)      // 64-bit mask words per row (=128)

typedef float f32x4 __attribute__((ext_vector_type(4)));
typedef __bf16 bf16x8 __attribute__((ext_vector_type(8)));
typedef unsigned long long ull;

__device__ __forceinline__ float lk(float x) { return x >= 0.f ? x : NEG_SLOPE * x; }

// ---------------------------------------------------------------------------
// K1: Wh = h@W (fp32). Outputs:
//   WhB bf16 in MFMA B-frag layout: WhB[(kg*64+n)*8+e] = bf16(Wh[kg*8+e][n])
//   f1 = Wh@a1, f2 = Wh@a2 (fp32)
// 256 thr, 16 rows/block. W in LDS (64KB); h read as wave-uniform f32x4.
// ---------------------------------------------------------------------------
__global__ __launch_bounds__(256) void gat_k1(const float* __restrict__ h,
                                              const float* __restrict__ W,
                                              const float* __restrict__ a,
                                              unsigned short* __restrict__ WhB,
                                              float* __restrict__ f1,
                                              float* __restrict__ f2) {
  __shared__ float Ws[FIN * FOUT];   // 64KB
  const int t = threadIdx.x;
  const int lane = t & 63;
  const int w = t >> 6;              // 0..3
  const size_t row0 = (size_t)blockIdx.x * 16;

  for (int i = t; i < FIN * FOUT / 4; i += 256)
    ((f32x4*)Ws)[i] = ((const f32x4*)W)[i];
  __syncthreads();

  const float* h0 = h + row0 * FIN;
  float acc[4] = {0.f, 0.f, 0.f, 0.f};   // rows w+4i, col = lane
  #pragma unroll 4
  for (int c4 = 0; c4 < FIN; c4 += 4) {
    const f32x4 hv0 = *(const f32x4*)(h0 + (w + 0)  * FIN + c4);
    const f32x4 hv1 = *(const f32x4*)(h0 + (w + 4)  * FIN + c4);
    const f32x4 hv2 = *(const f32x4*)(h0 + (w + 8)  * FIN + c4);
    const f32x4 hv3 = *(const f32x4*)(h0 + (w + 12) * FIN + c4);
    #pragma unroll
    for (int j = 0; j < 4; ++j) {
      const float wv = Ws[(c4 + j) * FOUT + lane];
      acc[0] = fmaf(hv0[j], wv, acc[0]);
      acc[1] = fmaf(hv1[j], wv, acc[1]);
      acc[2] = fmaf(hv2[j], wv, acc[2]);
      acc[3] = fmaf(hv3[j], wv, acc[3]);
    }
  }

  const float a1k = a[lane];
  const float a2k = a[FOUT + lane];
  #pragma unroll
  for (int i = 0; i < 4; ++i) {
    const size_t row = row0 + (w + 4 * i);
    WhB[(((row >> 3) * 64) + lane) * 8 + (row & 7)] =
        __builtin_bit_cast(unsigned short, __float2bfloat16(acc[i]));
    float p1 = acc[i] * a1k, p2 = acc[i] * a2k;
    #pragma unroll
    for (int off = 32; off; off >>= 1) {
      p1 += __shfl_down(p1, off);
      p2 += __shfl_down(p2, off);
    }
    if (lane == 0) { f1[row] = p1; f2[row] = p2; }
  }
}

// ---------------------------------------------------------------------------
// K2 (fused): per block of RB=8 rows, 4 waves, 1024 blocks (4 blocks/CU).
// Phase A: one adj sweep (NT loads), wave w -> rows 2w,2w+1: mask bits -> LDS,
//          row expsum (m=0; |f1+f2| bounded so no max pass needed) -> iz LDS.
// Phase B: per 256-col chunk: att = exp(lk(f1+f2))*iz masked -> NT store +
//          bf16 swizzled LDS tile (rows 8..15 zero-pad); PV via 8x
//          mfma_f32_16x16x32_bf16 per wave (wave w owns C cols w*16..).
// One barrier per chunk via double-buffered att tile.
// ---------------------------------------------------------------------------
__global__ __launch_bounds__(256) void gat_k2(const float* __restrict__ adj,
                                              const float* __restrict__ f1g,
                                              const float* __restrict__ f2g,
                                              const unsigned short* __restrict__ WhB,
                                              float* __restrict__ att,
                                              float* __restrict__ hp) {
  __shared__ ull msks[RB][MW];                                      // 8KB
  __shared__ __align__(16) unsigned char attb[2][16 * CHUNK * 2];   // 16KB
  __shared__ float izs[RB], f1s[RB];

  const int t = threadIdx.x;
  const int lane = t & 63;
  const int w = t >> 6;                  // 0..3
  const size_t row0 = (size_t)blockIdx.x * RB;

  // zero A-tile pad rows 8..15 of both buffers (never rewritten)
  for (int i = t; i < 1024; i += 256) {
    ((unsigned int*)(attb[0] + 8 * CHUNK * 2))[i] = 0u;
    ((unsigned int*)(attb[1] + 8 * CHUNK * 2))[i] = 0u;
  }

  // ---- phase A: adj sweep; wave w handles rows 2w, 2w+1
  #pragma unroll
  for (int rr = 0; rr < 2; ++rr) {
    const int r = 2 * w + rr;
    const float f1r = f1g[row0 + r];
    const f32x4* arow = (const f32x4*)(adj + (row0 + r) * (size_t)N);
    float s = 0.f;
    #pragma unroll 4
    for (int c = 0; c < NCHUNK; ++c) {
      const f32x4 v = __builtin_nontemporal_load(arow + c * 64 + lane);
      const f32x4 f = *(const f32x4*)&f2g[c * CHUNK + lane * 4];
      const ull b0 = __ballot(v.x > 0.f);
      const ull b1 = __ballot(v.y > 0.f);
      const ull b2 = __ballot(v.z > 0.f);
      const ull b3 = __ballot(v.w > 0.f);
      const ull bb = lane == 0 ? b0 : lane == 1 ? b1 : lane == 2 ? b2 : b3;
      if (lane < 4) msks[r][c * 4 + lane] = bb;
      s += (v.x > 0.f) ? __expf(lk(f1r + f.x)) : 0.f;
      s += (v.y > 0.f) ? __expf(lk(f1r + f.y)) : 0.f;
      s += (v.z > 0.f) ? __expf(lk(f1r + f.z)) : 0.f;
      s += (v.w > 0.f) ? __expf(lk(f1r + f.w)) : 0.f;
    }
    #pragma unroll
    for (int off = 32; off; off >>= 1) s += __shfl_xor(s, off);
    if (lane == 0) { izs[r] = 1.f / s; f1s[r] = f1r; }
  }
  __syncthreads();

  // ---- phase B
  float f1r_[2], z_[2];
  #pragma unroll
  for (int rr = 0; rr < 2; ++rr) {
    f1r_[rr] = f1s[2 * w + rr];
    z_[rr]   = izs[2 * w + rr];
  }

  f32x4 acc = {0.f, 0.f, 0.f, 0.f};
  #pragma unroll 2
  for (int c = 0; c < NCHUNK; ++c) {
    unsigned char* ab = attb[c & 1];
    const f32x4 f = *(const f32x4*)&f2g[c * CHUNK + lane * 4];
    #pragma unroll
    for (int rr = 0; rr < 2; ++rr) {
      const int r = 2 * w + rr;
      const ull b0 = msks[r][c * 4 + 0], b1 = msks[r][c * 4 + 1];
      const ull b2 = msks[r][c * 4 + 2], b3 = msks[r][c * 4 + 3];
      f32x4 p;
      p.x = ((b0 >> lane) & 1ull) ? __expf(lk(f1r_[rr] + f.x)) * z_[rr] : 0.f;
      p.y = ((b1 >> lane) & 1ull) ? __expf(lk(f1r_[rr] + f.y)) * z_[rr] : 0.f;
      p.z = ((b2 >> lane) & 1ull) ? __expf(lk(f1r_[rr] + f.z)) * z_[rr] : 0.f;
      p.w = ((b3 >> lane) & 1ull) ? __expf(lk(f1r_[rr] + f.w)) * z_[rr] : 0.f;
      __builtin_nontemporal_store(p, (f32x4*)(att + (row0 + r) * (size_t)N + c * CHUNK + lane * 4));
      const ull pk =
          (ull)__builtin_bit_cast(unsigned short, __float2bfloat16(p.x)) |
          ((ull)__builtin_bit_cast(unsigned short, __float2bfloat16(p.y)) << 16) |
          ((ull)__builtin_bit_cast(unsigned short, __float2bfloat16(p.z)) << 32) |
          ((ull)__builtin_bit_cast(unsigned short, __float2bfloat16(p.w)) << 48);
      int byte = r * (CHUNK * 2) + lane * 8;
      byte ^= (r & 7) << 4;
      *(ull*)(ab + byte) = pk;
    }
    __syncthreads();
    // ---- PV: 8 MFMA per wave (full K=256 of the chunk), C cols w*16..
    #pragma unroll
    for (int s8 = 0; s8 < 8; ++s8) {
      const int arow_ = lane & 15;
      int off = arow_ * (CHUNK * 2) + s8 * 64 + (lane >> 4) * 16;
      off ^= (arow_ & 7) << 4;
      const bf16x8 afrag = *(const bf16x8*)(ab + off);
      const int kg = c * 32 + s8 * 4 + (lane >> 4);
      const bf16x8 bfrag = *(const bf16x8*)(WhB + ((size_t)kg * 64 + w * 16 + (lane & 15)) * 8);
      acc = __builtin_amdgcn_mfma_f32_16x16x32_bf16(afrag, bfrag, acc, 0, 0, 0);
    }
    // no second barrier: next iter writes the other buffer; the c+2 overwrite
    // of this buffer is fenced by the barrier at c+1.
  }

  // ---- epilogue: C/D layout col = lane&15, row = (lane>>4)*4 + q; rows <8 valid
  const int col = w * 16 + (lane & 15);
  const int rbase = (lane >> 4) * 4;
  if (rbase < RB) {
    #pragma unroll
    for (int q = 0; q < 4; ++q)
      hp[(row0 + rbase + q) * FOUT + col] = acc[q];
  }
}

extern "C" void kernel_launch(void* const* d_in, const int* in_sizes, int n_in,
                              void* d_out, int out_size, void* d_ws, size_t ws_size,
                              hipStream_t stream) {
  const float* h   = (const float*)d_in[0];
  const float* adj = (const float*)d_in[1];
  const float* W   = (const float*)d_in[2];
  const float* a   = (const float*)d_in[3];

  float* hp  = (float*)d_out;                 // 8192*64
  float* att = hp + (size_t)N * FOUT;         // 8192*8192

  // workspace layout (~1.1MB)
  unsigned short* WhB = (unsigned short*)d_ws;                        // 1MB
  float* f1 = (float*)((char*)d_ws + (size_t)N * FOUT * 2);           // 32KB
  float* f2 = f1 + N;                                                 // 32KB

  gat_k1<<<N / 16, 256, 0, stream>>>(h, W, a, WhB, f1, f2);
  gat_k2<<<N / RB, 256, 0, stream>>>(adj, f1, f2, WhB, att, hp);
}